// Round 1
// baseline (874.015 us; speedup 1.0000x reference)
//
#include <hip/hip_runtime.h>
#include <math.h>

#define PI_F 3.14159265358979323846f

// Persistent device scratch (rewritten fully on every launch; avoids d_ws sizing
// assumptions). Layouts chosen for wave-uniform broadcast loads in k_main.
__device__ float g_rwT[576 * 64];  // res_proj_w transposed: [p][c]
__device__ float g_dwT[576 * 6];   // data_proj_w transposed: [p][q]
__device__ float g_Ur[64 * 64];    // fixed-circuit unitary, real part [t][s]
__device__ float g_Ui[64 * 64];    // imag part [t][s]
__device__ float g_Zw[64 * 64];    // Zw[t][c] = sum_q out_proj_w[c,q]*sign_q(t)
__device__ float g_sang[48];       // style angles [b][q], includes tanh*pi
__device__ float g_cb[64];         // out_proj_b + res_proj_b

// ---------------------------------------------------------------------------
// Weight transposes (grid-stride over the larger array).
__global__ void k_transpose(const float* __restrict__ dw, const float* __restrict__ rw) {
    int i = blockIdx.x * 256 + threadIdx.x;
    if (i < 576 * 6)  { int q = i / 576, p = i % 576; g_dwT[p * 6  + q] = dw[i]; }
    if (i < 576 * 64) { int c = i / 576, p = i % 576; g_rwT[p * 64 + c] = rw[i]; }
}

// ---------------------------------------------------------------------------
// One block, 64 threads. Thread s simulates the fixed circuit on basis state
// e_s, producing column s of U. Also builds Zw, cb, and per-batch style angles.
__global__ void k_setup(const float* __restrict__ style,
                        const float* __restrict__ s2dw, const float* __restrict__ s2db,
                        const float* __restrict__ qcnn, const float* __restrict__ meas,
                        const float* __restrict__ outw, const float* __restrict__ outb,
                        const float* __restrict__ resb) {
    int s = threadIdx.x;  // 0..63
    float ar[64], ai[64];
#pragma unroll
    for (int t = 0; t < 64; ++t) { ar[t] = (t == s) ? 1.f : 0.f; ai[t] = 0.f; }

    // HEA layers: per-wire RY, RZ (scalar params), then ring CNOTs.
#pragma unroll
    for (int l = 0; l < 2; ++l) {
#pragma unroll
        for (int wq = 0; wq < 6; ++wq) {
            int mask = 1 << (5 - wq);  // wire wq = bit (5-wq) of state index
            float th = qcnn[((l * 6 + wq) * 2 + 0) * 3];
            float sg, cg; sincosf(0.5f * th, &sg, &cg);
#pragma unroll
            for (int t = 0; t < 64; ++t) {
                if (t & mask) continue;
                int u = t | mask;
                float a0r = ar[t], a0i = ai[t], a1r = ar[u], a1i = ai[u];
                ar[t] = cg * a0r - sg * a1r;  ai[t] = cg * a0i - sg * a1i;
                ar[u] = sg * a0r + cg * a1r;  ai[u] = sg * a0i + cg * a1i;
            }
            float ph = qcnn[((l * 6 + wq) * 2 + 1) * 3];
            float sz, cz; sincosf(0.5f * ph, &sz, &cz);
#pragma unroll
            for (int t = 0; t < 64; ++t) {
                float r = ar[t], im = ai[t];
                if (t & mask) { ar[t] = cz * r - sz * im; ai[t] = cz * im + sz * r; }
                else          { ar[t] = cz * r + sz * im; ai[t] = cz * im - sz * r; }
            }
        }
#pragma unroll
        for (int wq = 0; wq < 6; ++wq) {
            int cm = 1 << (5 - wq);
            int tm = 1 << (5 - ((wq + 1) % 6));
#pragma unroll
            for (int t = 0; t < 64; ++t) {
                if ((t & cm) && !(t & tm)) {
                    int u = t | tm;
                    float r = ar[t], im = ai[t];
                    ar[t] = ar[u]; ai[t] = ai[u];
                    ar[u] = r;     ai[u] = im;
                }
            }
        }
    }
    // Measurement basis: U3(theta, phi, lam) per wire.
#pragma unroll
    for (int wq = 0; wq < 6; ++wq) {
        int mask = 1 << (5 - wq);
        float th = meas[wq * 3 + 0], ph = meas[wq * 3 + 1], lm = meas[wq * 3 + 2];
        float st2, ct; sincosf(0.5f * th, &st2, &ct);
        float sl, cl;  sincosf(lm, &sl, &cl);
        float sp, cp;  sincosf(ph, &sp, &cp);
        float spl, cpl; sincosf(ph + lm, &spl, &cpl);
        float u01r = -cl * st2, u01i = -sl * st2;
        float u10r =  cp * st2, u10i =  sp * st2;
        float u11r =  cpl * ct, u11i =  spl * ct;
#pragma unroll
        for (int t = 0; t < 64; ++t) {
            if (t & mask) continue;
            int u = t | mask;
            float a0r = ar[t], a0i = ai[t], a1r = ar[u], a1i = ai[u];
            ar[t] = ct * a0r + u01r * a1r - u01i * a1i;
            ai[t] = ct * a0i + u01r * a1i + u01i * a1r;
            ar[u] = u10r * a0r - u10i * a0i + u11r * a1r - u11i * a1i;
            ai[u] = u10r * a0i + u10i * a0r + u11r * a1i + u11i * a1r;
        }
    }
#pragma unroll
    for (int t = 0; t < 64; ++t) { g_Ur[t * 64 + s] = ar[t]; g_Ui[t * 64 + s] = ai[t]; }

    // Zw row t=s: fold out_proj_w with PauliZ sign patterns.
#pragma unroll
    for (int c = 0; c < 64; ++c) {
        float z = 0.f;
#pragma unroll
        for (int q = 0; q < 6; ++q) {
            float sgn = ((s >> (5 - q)) & 1) ? -1.f : 1.f;
            z += outw[c * 6 + q] * sgn;
        }
        g_Zw[s * 64 + c] = z;
    }
    g_cb[s] = outb[s] + resb[s];

    // Per-batch style angles (8 batches x 6 qubits).
    if (s < 48) {
        int bb = s / 6, q = s % 6;
        float a = s2db[q];
        for (int k = 0; k < 128; ++k) a += style[bb * 128 + k] * s2dw[q * 128 + k];
        g_sang[s] = tanhf(a) * PI_F;
    }
}

// ---------------------------------------------------------------------------
// Main: 64 pixels per block, 4 K-slices (one wave each) per pixel group.
// Slice handles input channels [16*slice,16*slice+16) for the projections and
// output states [16*slice,16*slice+16) for the quantum contraction.
__global__ __launch_bounds__(256, 2) void k_main(const float* __restrict__ x,
                                                 const float* __restrict__ dpb,
                                                 float* __restrict__ out) {
    __shared__ float lds_out[64 * 65];  // [pixel][c], stride 65 = conflict-free
    __shared__ float lds_ang[6 * 256];  // [q][slice*64+lane]

    int lane  = threadIdx.x & 63;
    int slice = threadIdx.x >> 6;
    int p = blockIdx.x * 64 + lane;     // global pixel id: b*4096 + h*64 + w
    int b = p >> 12;
    int h = (p >> 6) & 63;
    int w = p & 63;
    const float* xb = x + (b << 18);

    float acc[64];
#pragma unroll
    for (int c = 0; c < 64; ++c) acc[c] = 0.f;
    float ang[6] = {0.f, 0.f, 0.f, 0.f, 0.f, 0.f};

    // Patch pass over this slice's 16 channels x 9 kernel positions.
    int c0 = slice * 16;
    for (int ci = 0; ci < 16; ++ci) {
        int c = c0 + ci;
        const float* xc = xb + (c << 12);
#pragma unroll
        for (int i = 0; i < 3; ++i) {
            int hh = h + i - 1;
            bool hok = (unsigned)hh < 64u;
#pragma unroll
            for (int j = 0; j < 3; ++j) {
                int ww = w + j - 1;
                float v = 0.f;
                if (hok && (unsigned)ww < 64u) v = xc[(hh << 6) + ww];
                int pi = c * 9 + i * 3 + j;
                const float* dwp = g_dwT + pi * 6;
#pragma unroll
                for (int q = 0; q < 6; ++q) ang[q] += v * dwp[q];
                const float* rwp = g_rwT + (pi << 6);
#pragma unroll
                for (int c2 = 0; c2 < 64; ++c2) acc[c2] += v * rwp[c2];
            }
        }
    }

    // Reduce the 4 partial angle vectors per pixel.
#pragma unroll
    for (int q = 0; q < 6; ++q) lds_ang[q * 256 + slice * 64 + lane] = ang[q];
    __syncthreads();
    float theta[6];
#pragma unroll
    for (int q = 0; q < 6; ++q) {
        const float* a = lds_ang + q * 256 + lane;
        float t = a[0] + a[64] + a[128] + a[192];
        theta[q] = tanhf(t + dpb[q]) * PI_F + g_sang[b * 6 + q];
    }

    // psi0 = product state (real), wire 0 = MSB of state index.
    float psi[64];
    psi[0] = 1.f;
#pragma unroll
    for (int q = 0; q < 6; ++q) {
        float sq, cq; sincosf(0.5f * theta[q], &sq, &cq);
#pragma unroll
        for (int r = (1 << q) - 1; r >= 0; --r) {
            float t = psi[r];
            psi[2 * r + 1] = t * sq;
            psi[2 * r]     = t * cq;
        }
    }

    // Quantum contraction for this slice's 16 output states t.
    int t0 = slice * 16;
    for (int ti = 0; ti < 16; ++ti) {
        int t = t0 + ti;
        const float* ur = g_Ur + (t << 6);
        const float* ui = g_Ui + (t << 6);
        float yr = 0.f, yi = 0.f;
#pragma unroll
        for (int s = 0; s < 64; ++s) { yr += ur[s] * psi[s]; yi += ui[s] * psi[s]; }
        float prob = yr * yr + yi * yi;
        const float* zw = g_Zw + (t << 6);
#pragma unroll
        for (int c2 = 0; c2 < 64; ++c2) acc[c2] += prob * zw[c2];
    }

    // 4-way rotating reduction into LDS (all slices active, disjoint quarters).
#pragma unroll
    for (int r = 0; r < 4; ++r) {
        int cq = ((slice + r) & 3) << 4;
        if (r == 0) {
#pragma unroll
            for (int k = 0; k < 16; ++k) lds_out[lane * 65 + cq + k] = acc[cq + k];
        } else {
#pragma unroll
            for (int k = 0; k < 16; ++k) lds_out[lane * 65 + cq + k] += acc[cq + k];
        }
        __syncthreads();
    }

    // Coalesced store: out[b][c][h][w].
    int ob = (b << 18) + (h << 6) + w;
#pragma unroll
    for (int k = 0; k < 16; ++k) {
        int c = c0 + k;
        out[ob + (c << 12)] = lds_out[lane * 65 + c] + g_cb[c];
    }
}

// ---------------------------------------------------------------------------
extern "C" void kernel_launch(void* const* d_in, const int* in_sizes, int n_in,
                              void* d_out, int out_size, void* d_ws, size_t ws_size,
                              hipStream_t stream) {
    const float* x     = (const float*)d_in[0];
    const float* style = (const float*)d_in[1];
    const float* dw    = (const float*)d_in[2];
    const float* dpb   = (const float*)d_in[3];
    const float* s2dw  = (const float*)d_in[4];
    const float* s2db  = (const float*)d_in[5];
    const float* qcnn  = (const float*)d_in[6];
    const float* meas  = (const float*)d_in[7];
    const float* outw  = (const float*)d_in[8];
    const float* outb  = (const float*)d_in[9];
    const float* rw    = (const float*)d_in[10];
    const float* resb  = (const float*)d_in[11];
    float* out = (float*)d_out;

    hipLaunchKernelGGL(k_transpose, dim3(144), dim3(256), 0, stream, dw, rw);
    hipLaunchKernelGGL(k_setup, dim3(1), dim3(64), 0, stream,
                       style, s2dw, s2db, qcnn, meas, outw, outb, resb);
    hipLaunchKernelGGL(k_main, dim3(512), dim3(256), 0, stream, x, dpb, out);
}

// Round 2
// 500.613 us; speedup vs baseline: 1.7459x; 1.7459x over previous
//
#include <hip/hip_runtime.h>
#include <math.h>

#define PI_F 3.14159265358979323846f

// Persistent device scratch (rewritten fully on every launch).
__device__ float g_rwT[576 * 64];  // res_proj_w transposed: [p][c]
__device__ float g_dwT[576 * 6];   // data_proj_w transposed: [p][q]
__device__ float g_Ur[64 * 64];    // fixed-circuit unitary, real part [t][s]
__device__ float g_Ui[64 * 64];    // imag part [t][s]
__device__ float g_Zw[64 * 64];    // Zw[t][c] = sum_q out_proj_w[c,q]*sign_q(t)
__device__ float g_sang[48];       // style angles [b][q] (tanh*pi applied)
__device__ float g_cb[64];         // out_proj_b + res_proj_b

// ---------------------------------------------------------------------------
// Combined prep. Block 0: circuit unitary (wave 0) + style angles (waves 1-3).
// Blocks >= 1: weight transposes.
__global__ void k_prep(const float* __restrict__ style,
                       const float* __restrict__ dw, const float* __restrict__ rw,
                       const float* __restrict__ s2dw, const float* __restrict__ s2db,
                       const float* __restrict__ qcnn, const float* __restrict__ meas,
                       const float* __restrict__ outw, const float* __restrict__ outb,
                       const float* __restrict__ resb) {
    if (blockIdx.x > 0) {
        int i = (blockIdx.x - 1) * 256 + threadIdx.x;
        if (i < 576 * 6)  { int q = i / 576, p = i % 576; g_dwT[p * 6  + q] = dw[i]; }
        if (i < 576 * 64) { int c = i / 576, p = i % 576; g_rwT[p * 64 + c] = rw[i]; }
        return;
    }
    int s = threadIdx.x;
    if (s >= 64) {
        int k = s - 64;  // style angles: 48 outputs on waves 1-3
        if (k < 48) {
            int bb = k / 6, q = k % 6;
            float a = s2db[q];
            for (int j = 0; j < 128; ++j) a += style[bb * 128 + j] * s2dw[q * 128 + j];
            g_sang[k] = tanhf(a) * PI_F;
        }
        return;
    }
    // Wave 0, lane s: simulate fixed circuit on basis state e_s -> column s of U.
    float ar[64], ai[64];
#pragma unroll
    for (int t = 0; t < 64; ++t) { ar[t] = (t == s) ? 1.f : 0.f; ai[t] = 0.f; }

#pragma unroll
    for (int l = 0; l < 2; ++l) {
#pragma unroll
        for (int wq = 0; wq < 6; ++wq) {
            int mask = 1 << (5 - wq);  // wire wq = bit (5-wq) of state index
            float th = qcnn[((l * 6 + wq) * 2 + 0) * 3];
            float sg, cg; sincosf(0.5f * th, &sg, &cg);
#pragma unroll
            for (int t = 0; t < 64; ++t) {
                if (t & mask) continue;
                int u = t | mask;
                float a0r = ar[t], a0i = ai[t], a1r = ar[u], a1i = ai[u];
                ar[t] = cg * a0r - sg * a1r;  ai[t] = cg * a0i - sg * a1i;
                ar[u] = sg * a0r + cg * a1r;  ai[u] = sg * a0i + cg * a1i;
            }
            float ph = qcnn[((l * 6 + wq) * 2 + 1) * 3];
            float sz, cz; sincosf(0.5f * ph, &sz, &cz);
#pragma unroll
            for (int t = 0; t < 64; ++t) {
                float r = ar[t], im = ai[t];
                if (t & mask) { ar[t] = cz * r - sz * im; ai[t] = cz * im + sz * r; }
                else          { ar[t] = cz * r + sz * im; ai[t] = cz * im - sz * r; }
            }
        }
#pragma unroll
        for (int wq = 0; wq < 6; ++wq) {
            int cm = 1 << (5 - wq);
            int tm = 1 << (5 - ((wq + 1) % 6));
#pragma unroll
            for (int t = 0; t < 64; ++t) {
                if ((t & cm) && !(t & tm)) {
                    int u = t | tm;
                    float r = ar[t], im = ai[t];
                    ar[t] = ar[u]; ai[t] = ai[u];
                    ar[u] = r;     ai[u] = im;
                }
            }
        }
    }
#pragma unroll
    for (int wq = 0; wq < 6; ++wq) {
        int mask = 1 << (5 - wq);
        float th = meas[wq * 3 + 0], ph = meas[wq * 3 + 1], lm = meas[wq * 3 + 2];
        float st2, ct; sincosf(0.5f * th, &st2, &ct);
        float sl, cl;  sincosf(lm, &sl, &cl);
        float sp, cp;  sincosf(ph, &sp, &cp);
        float spl, cpl; sincosf(ph + lm, &spl, &cpl);
        float u01r = -cl * st2, u01i = -sl * st2;
        float u10r =  cp * st2, u10i =  sp * st2;
        float u11r =  cpl * ct, u11i =  spl * ct;
#pragma unroll
        for (int t = 0; t < 64; ++t) {
            if (t & mask) continue;
            int u = t | mask;
            float a0r = ar[t], a0i = ai[t], a1r = ar[u], a1i = ai[u];
            ar[t] = ct * a0r + u01r * a1r - u01i * a1i;
            ai[t] = ct * a0i + u01r * a1i + u01i * a1r;
            ar[u] = u10r * a0r - u10i * a0i + u11r * a1r - u11i * a1i;
            ai[u] = u10r * a0i + u10i * a0r + u11r * a1i + u11i * a1r;
        }
    }
#pragma unroll
    for (int t = 0; t < 64; ++t) { g_Ur[t * 64 + s] = ar[t]; g_Ui[t * 64 + s] = ai[t]; }

#pragma unroll
    for (int c = 0; c < 64; ++c) {
        float z = 0.f;
#pragma unroll
        for (int q = 0; q < 6; ++q) {
            float sgn = ((s >> (5 - q)) & 1) ? -1.f : 1.f;
            z += outw[c * 6 + q] * sgn;
        }
        g_Zw[s * 64 + c] = z;
    }
    g_cb[s] = outb[s] + resb[s];
}

// ---------------------------------------------------------------------------
// Main: 64 pixels per block (one h-row slice), 8 slices (waves) per block.
// Slice owns OUTPUT channels [8*slice, 8*slice+8) and probability states
// [8*slice, 8*slice+8). acc[8] + psi[64] stay register-resident; all
// thread-array indexing is compile-time (no scratch).
__global__ __launch_bounds__(512, 4) void k_main(const float* __restrict__ x,
                                                 const float* __restrict__ dpb,
                                                 float* __restrict__ out) {
    __shared__ float lds_ang[6 * 512];   // [q][thread]
    __shared__ float lds_prob[64 * 65];  // [pixel][t], stride 65

    int lane  = threadIdx.x & 63;
    int slice = threadIdx.x >> 6;        // 0..7
    int p = blockIdx.x * 64 + lane;      // pixel id: b*4096 + h*64 + w
    int b = p >> 12;
    int h = (p >> 6) & 63;
    int w = p & 63;
    const float* xb = x + (b << 18);
    int c0 = slice * 8;

    // ---- pass 1: data-angle partials over this slice's 8 input channels
    float ang[6] = {0.f, 0.f, 0.f, 0.f, 0.f, 0.f};
    for (int ci = 0; ci < 8; ++ci) {
        int c = c0 + ci;
        const float* xc = xb + (c << 12);
#pragma unroll
        for (int i = 0; i < 3; ++i) {
            int hh = h + i - 1;
            bool hok = (unsigned)hh < 64u;
#pragma unroll
            for (int j = 0; j < 3; ++j) {
                int ww = w + j - 1;
                float v = (hok && (unsigned)ww < 64u) ? xc[(hh << 6) + ww] : 0.f;
                const float* dwp = g_dwT + (c * 9 + i * 3 + j) * 6;
#pragma unroll
                for (int q = 0; q < 6; ++q) ang[q] += v * dwp[q];
            }
        }
    }
#pragma unroll
    for (int q = 0; q < 6; ++q) lds_ang[q * 512 + threadIdx.x] = ang[q];

    // ---- pass 2: res conv, full K sweep, 8 OUTPUT channels per thread
    float acc[8];
#pragma unroll
    for (int k = 0; k < 8; ++k) acc[k] = 0.f;
#pragma unroll
    for (int i = 0; i < 3; ++i) {
        int hh = h + i - 1;
        bool hok = (unsigned)hh < 64u;
#pragma unroll
        for (int j = 0; j < 3; ++j) {
            int ww = w + j - 1;
            bool ok = hok && (unsigned)ww < 64u;
            const float* xij = xb + (hh << 6) + ww;
            const float* wij = g_rwT + ((i * 3 + j) << 6) + c0;  // row (c*9+ij), cols c0..c0+7
#pragma unroll 4
            for (int c = 0; c < 64; ++c) {
                float v = ok ? xij[c << 12] : 0.f;
                const float4 w0 = *(const float4*)(wij + c * 576);
                const float4 w1 = *(const float4*)(wij + c * 576 + 4);
                acc[0] += v * w0.x; acc[1] += v * w0.y;
                acc[2] += v * w0.z; acc[3] += v * w0.w;
                acc[4] += v * w1.x; acc[5] += v * w1.y;
                acc[6] += v * w1.z; acc[7] += v * w1.w;
            }
        }
    }

    // ---- reduce angles across the 8 slices, finish theta
    __syncthreads();
    float theta[6];
#pragma unroll
    for (int q = 0; q < 6; ++q) {
        const float* a = lds_ang + q * 512 + lane;
        float t = 0.f;
#pragma unroll
        for (int s2 = 0; s2 < 8; ++s2) t += a[s2 * 64];
        theta[q] = tanhf(t + dpb[q]) * PI_F + g_sang[b * 6 + q];
    }

    // ---- psi0 = real product state (wire 0 = MSB), fully unrolled
    float psi[64];
    psi[0] = 1.f;
#pragma unroll
    for (int q = 0; q < 6; ++q) {
        float sq, cq; sincosf(0.5f * theta[q], &sq, &cq);
#pragma unroll
        for (int r = (1 << q) - 1; r >= 0; --r) {
            float t = psi[r];
            psi[2 * r + 1] = t * sq;
            psi[2 * r]     = t * cq;
        }
    }

    // ---- probs for this slice's 8 states -> LDS
#pragma unroll
    for (int ti = 0; ti < 8; ++ti) {
        int t = c0 + ti;
        const float4* ur = (const float4*)(g_Ur + (t << 6));
        const float4* ui = (const float4*)(g_Ui + (t << 6));
        float yr = 0.f, yi = 0.f;
#pragma unroll
        for (int s2 = 0; s2 < 16; ++s2) {
            float4 u4 = ur[s2];
            float4 v4 = ui[s2];
            yr += u4.x * psi[4 * s2] + u4.y * psi[4 * s2 + 1]
                + u4.z * psi[4 * s2 + 2] + u4.w * psi[4 * s2 + 3];
            yi += v4.x * psi[4 * s2] + v4.y * psi[4 * s2 + 1]
                + v4.z * psi[4 * s2 + 2] + v4.w * psi[4 * s2 + 3];
        }
        lds_prob[lane * 65 + t] = yr * yr + yi * yi;
    }
    __syncthreads();

    // ---- fold probs through Zw into this slice's 8 output channels
#pragma unroll 8
    for (int t = 0; t < 64; ++t) {
        float pr = lds_prob[lane * 65 + t];
        const float4 z0 = *(const float4*)(g_Zw + (t << 6) + c0);
        const float4 z1 = *(const float4*)(g_Zw + (t << 6) + c0 + 4);
        acc[0] += pr * z0.x; acc[1] += pr * z0.y;
        acc[2] += pr * z0.z; acc[3] += pr * z0.w;
        acc[4] += pr * z1.x; acc[5] += pr * z1.y;
        acc[6] += pr * z1.z; acc[7] += pr * z1.w;
    }

    // ---- coalesced store: out[b][c][h][w]
    int ob = (b << 18) + (h << 6) + w;
#pragma unroll
    for (int k = 0; k < 8; ++k) {
        out[ob + ((c0 + k) << 12)] = acc[k] + g_cb[c0 + k];
    }
}

// ---------------------------------------------------------------------------
extern "C" void kernel_launch(void* const* d_in, const int* in_sizes, int n_in,
                              void* d_out, int out_size, void* d_ws, size_t ws_size,
                              hipStream_t stream) {
    const float* x     = (const float*)d_in[0];
    const float* style = (const float*)d_in[1];
    const float* dw    = (const float*)d_in[2];
    const float* dpb   = (const float*)d_in[3];
    const float* s2dw  = (const float*)d_in[4];
    const float* s2db  = (const float*)d_in[5];
    const float* qcnn  = (const float*)d_in[6];
    const float* meas  = (const float*)d_in[7];
    const float* outw  = (const float*)d_in[8];
    const float* outb  = (const float*)d_in[9];
    const float* rw    = (const float*)d_in[10];
    const float* resb  = (const float*)d_in[11];
    float* out = (float*)d_out;

    hipLaunchKernelGGL(k_prep, dim3(145), dim3(256), 0, stream,
                       style, dw, rw, s2dw, s2db, qcnn, meas, outw, outb, resb);
    hipLaunchKernelGGL(k_main, dim3(512), dim3(512), 0, stream, x, dpb, out);
}

// Round 3
// 264.883 us; speedup vs baseline: 3.2996x; 1.8899x over previous
//
#include <hip/hip_runtime.h>
#include <math.h>

#define PI_F 3.14159265358979323846f

// Persistent device scratch (rewritten fully on every launch).
__device__ float g_rwT[576 * 64];  // res_proj_w transposed: [p][c]
__device__ float g_dwT[576 * 6];   // data_proj_w transposed: [p][q]
__device__ float g_Ur[64 * 64];    // fixed-circuit unitary, real part [t][s]
__device__ float g_Ui[64 * 64];    // imag part [t][s]
__device__ float g_Zw[64 * 64];    // Zw[t][c] = sum_q out_proj_w[c,q]*sign_q(t)
__device__ float g_sang[48];       // style angles [b][q] (tanh*pi applied)
__device__ float g_cb[64];         // out_proj_b + res_proj_b

// ---------------------------------------------------------------------------
// Combined prep. Block 0: circuit unitary (wave 0) + style angles (waves 1-3).
// Blocks >= 1: weight transposes.
__global__ void k_prep(const float* __restrict__ style,
                       const float* __restrict__ dw, const float* __restrict__ rw,
                       const float* __restrict__ s2dw, const float* __restrict__ s2db,
                       const float* __restrict__ qcnn, const float* __restrict__ meas,
                       const float* __restrict__ outw, const float* __restrict__ outb,
                       const float* __restrict__ resb) {
    if (blockIdx.x > 0) {
        int i = (blockIdx.x - 1) * 256 + threadIdx.x;
        if (i < 576 * 6)  { int q = i / 576, p = i % 576; g_dwT[p * 6  + q] = dw[i]; }
        if (i < 576 * 64) { int c = i / 576, p = i % 576; g_rwT[p * 64 + c] = rw[i]; }
        return;
    }
    int s = threadIdx.x;
    if (s >= 64) {
        int k = s - 64;  // style angles: 48 outputs on waves 1-3
        if (k < 48) {
            int bb = k / 6, q = k % 6;
            float a = s2db[q];
            for (int j = 0; j < 128; ++j) a += style[bb * 128 + j] * s2dw[q * 128 + j];
            g_sang[k] = tanhf(a) * PI_F;
        }
        return;
    }
    // Wave 0, lane s: simulate fixed circuit on basis state e_s -> column s of U.
    float ar[64], ai[64];
#pragma unroll
    for (int t = 0; t < 64; ++t) { ar[t] = (t == s) ? 1.f : 0.f; ai[t] = 0.f; }

#pragma unroll
    for (int l = 0; l < 2; ++l) {
#pragma unroll
        for (int wq = 0; wq < 6; ++wq) {
            int mask = 1 << (5 - wq);  // wire wq = bit (5-wq) of state index
            float th = qcnn[((l * 6 + wq) * 2 + 0) * 3];
            float sg, cg; sincosf(0.5f * th, &sg, &cg);
#pragma unroll
            for (int t = 0; t < 64; ++t) {
                if (t & mask) continue;
                int u = t | mask;
                float a0r = ar[t], a0i = ai[t], a1r = ar[u], a1i = ai[u];
                ar[t] = cg * a0r - sg * a1r;  ai[t] = cg * a0i - sg * a1i;
                ar[u] = sg * a0r + cg * a1r;  ai[u] = sg * a0i + cg * a1i;
            }
            float ph = qcnn[((l * 6 + wq) * 2 + 1) * 3];
            float sz, cz; sincosf(0.5f * ph, &sz, &cz);
#pragma unroll
            for (int t = 0; t < 64; ++t) {
                float r = ar[t], im = ai[t];
                if (t & mask) { ar[t] = cz * r - sz * im; ai[t] = cz * im + sz * r; }
                else          { ar[t] = cz * r + sz * im; ai[t] = cz * im - sz * r; }
            }
        }
#pragma unroll
        for (int wq = 0; wq < 6; ++wq) {
            int cm = 1 << (5 - wq);
            int tm = 1 << (5 - ((wq + 1) % 6));
#pragma unroll
            for (int t = 0; t < 64; ++t) {
                if ((t & cm) && !(t & tm)) {
                    int u = t | tm;
                    float r = ar[t], im = ai[t];
                    ar[t] = ar[u]; ai[t] = ai[u];
                    ar[u] = r;     ai[u] = im;
                }
            }
        }
    }
#pragma unroll
    for (int wq = 0; wq < 6; ++wq) {
        int mask = 1 << (5 - wq);
        float th = meas[wq * 3 + 0], ph = meas[wq * 3 + 1], lm = meas[wq * 3 + 2];
        float st2, ct; sincosf(0.5f * th, &st2, &ct);
        float sl, cl;  sincosf(lm, &sl, &cl);
        float sp, cp;  sincosf(ph, &sp, &cp);
        float spl, cpl; sincosf(ph + lm, &spl, &cpl);
        float u01r = -cl * st2, u01i = -sl * st2;
        float u10r =  cp * st2, u10i =  sp * st2;
        float u11r =  cpl * ct, u11i =  spl * ct;
#pragma unroll
        for (int t = 0; t < 64; ++t) {
            if (t & mask) continue;
            int u = t | mask;
            float a0r = ar[t], a0i = ai[t], a1r = ar[u], a1i = ai[u];
            ar[t] = ct * a0r + u01r * a1r - u01i * a1i;
            ai[t] = ct * a0i + u01r * a1i + u01i * a1r;
            ar[u] = u10r * a0r - u10i * a0i + u11r * a1r - u11i * a1i;
            ai[u] = u10r * a0i + u10i * a0r + u11r * a1i + u11i * a1r;
        }
    }
#pragma unroll
    for (int t = 0; t < 64; ++t) { g_Ur[t * 64 + s] = ar[t]; g_Ui[t * 64 + s] = ai[t]; }

#pragma unroll
    for (int c = 0; c < 64; ++c) {
        float z = 0.f;
#pragma unroll
        for (int q = 0; q < 6; ++q) {
            float sgn = ((s >> (5 - q)) & 1) ? -1.f : 1.f;
            z += outw[c * 6 + q] * sgn;
        }
        g_Zw[s * 64 + c] = z;
    }
    g_cb[s] = outb[s] + resb[s];
}

// ---------------------------------------------------------------------------
// Main: 64 pixels per block (one h-row), 8 slices (waves). Slice owns OUTPUT
// channels / states [8*slice, 8*slice+8). No thread-private array larger than
// 8; psi lives in LDS (computed cooperatively as 6-factor products).
__global__ __launch_bounds__(512, 4) void k_main(const float* __restrict__ x,
                                                 const float* __restrict__ dpb,
                                                 float* __restrict__ out) {
    __shared__ float lds_ang[6 * 512];   // [q][thread]
    __shared__ float lds_psi[64 * 65];   // [pixel][s], stride 65
    __shared__ float lds_prob[64 * 65];  // [pixel][t], stride 65

    int lane  = threadIdx.x & 63;
    // Force wave-uniform values into SGPRs so all weight/U/Zw addresses are
    // scalar loads (s_load), keeping the vector-mem pipe free for x.
    int slice = __builtin_amdgcn_readfirstlane(threadIdx.x >> 6);  // 0..7
    int c0 = slice * 8;

    int p = blockIdx.x * 64 + lane;      // pixel id: b*4096 + h*64 + w
    int b = p >> 12;
    int h = (p >> 6) & 63;
    int w = p & 63;
    const float* xb = x + (b << 18);

    // ---- pass 1: data-angle partials over this slice's 8 input channels
    float ang[6] = {0.f, 0.f, 0.f, 0.f, 0.f, 0.f};
    for (int ci = 0; ci < 8; ++ci) {
        int c = c0 + ci;
        const float* xc = xb + (c << 12);
#pragma unroll
        for (int i = 0; i < 3; ++i) {
            int hh = h + i - 1;
            bool hok = (unsigned)hh < 64u;
#pragma unroll
            for (int j = 0; j < 3; ++j) {
                int ww = w + j - 1;
                float v = 0.f;
                if (hok && (unsigned)ww < 64u) v = xc[(hh << 6) + ww];
                const float* dwp = g_dwT + (c * 9 + i * 3 + j) * 6;
#pragma unroll
                for (int q = 0; q < 6; ++q) ang[q] += v * dwp[q];
            }
        }
    }
#pragma unroll
    for (int q = 0; q < 6; ++q) lds_ang[q * 512 + threadIdx.x] = ang[q];

    // ---- pass 2: res conv, full K sweep, 8 OUTPUT channels per thread
    float acc[8];
#pragma unroll
    for (int k = 0; k < 8; ++k) acc[k] = 0.f;
#pragma unroll
    for (int i = 0; i < 3; ++i) {
        int hh = h + i - 1;
        bool hok = (unsigned)hh < 64u;
#pragma unroll
        for (int j = 0; j < 3; ++j) {
            int ww = w + j - 1;
            bool ok = hok && (unsigned)ww < 64u;
            const float* xij = xb + (hh << 6) + ww;
            const float* wij = g_rwT + ((i * 3 + j) << 6) + c0;  // + c*576
#pragma unroll 4
            for (int c = 0; c < 64; ++c) {
                float v = 0.f;
                if (ok) v = xij[c << 12];
                const float4 w0 = *(const float4*)(wij + c * 576);
                const float4 w1 = *(const float4*)(wij + c * 576 + 4);
                acc[0] += v * w0.x; acc[1] += v * w0.y;
                acc[2] += v * w0.z; acc[3] += v * w0.w;
                acc[4] += v * w1.x; acc[5] += v * w1.y;
                acc[6] += v * w1.z; acc[7] += v * w1.w;
            }
        }
    }

    // ---- reduce angles across the 8 slices, finish theta, sincos
    __syncthreads();
    float sc[6], cc[6];
#pragma unroll
    for (int q = 0; q < 6; ++q) {
        const float* a = lds_ang + q * 512 + lane;
        float t = 0.f;
#pragma unroll
        for (int s2 = 0; s2 < 8; ++s2) t += a[s2 * 64];
        float theta = tanhf(t + dpb[q]) * PI_F + g_sang[b * 6 + q];
        sincosf(0.5f * theta, &sc[q], &cc[q]);
    }

    // ---- cooperative psi: this thread builds states s = c0..c0+7 as
    // 6-factor products (wire q = bit (5-q) of s).
#pragma unroll
    for (int ti = 0; ti < 8; ++ti) {
        int s = c0 + ti;
        float v = ((s >> 5) & 1) ? sc[0] : cc[0];
        v *= ((s >> 4) & 1) ? sc[1] : cc[1];
        v *= ((s >> 3) & 1) ? sc[2] : cc[2];
        v *= ((s >> 2) & 1) ? sc[3] : cc[3];
        v *= ((s >> 1) & 1) ? sc[4] : cc[4];
        v *= (s & 1)        ? sc[5] : cc[5];
        lds_psi[lane * 65 + s] = v;
    }
    __syncthreads();

    // ---- probs for this slice's 8 states: stream psi from LDS in blocks of 8
    float yr[8], yi[8];
#pragma unroll
    for (int t = 0; t < 8; ++t) { yr[t] = 0.f; yi[t] = 0.f; }
#pragma unroll
    for (int s0 = 0; s0 < 8; ++s0) {
        float ps[8];
#pragma unroll
        for (int k = 0; k < 8; ++k) ps[k] = lds_psi[lane * 65 + s0 * 8 + k];
#pragma unroll
        for (int t = 0; t < 8; ++t) {
            const float4 u0 = *(const float4*)(g_Ur + ((c0 + t) << 6) + s0 * 8);
            const float4 u1 = *(const float4*)(g_Ur + ((c0 + t) << 6) + s0 * 8 + 4);
            const float4 v0 = *(const float4*)(g_Ui + ((c0 + t) << 6) + s0 * 8);
            const float4 v1 = *(const float4*)(g_Ui + ((c0 + t) << 6) + s0 * 8 + 4);
            yr[t] += u0.x * ps[0] + u0.y * ps[1] + u0.z * ps[2] + u0.w * ps[3]
                   + u1.x * ps[4] + u1.y * ps[5] + u1.z * ps[6] + u1.w * ps[7];
            yi[t] += v0.x * ps[0] + v0.y * ps[1] + v0.z * ps[2] + v0.w * ps[3]
                   + v1.x * ps[4] + v1.y * ps[5] + v1.z * ps[6] + v1.w * ps[7];
        }
    }
#pragma unroll
    for (int t = 0; t < 8; ++t)
        lds_prob[lane * 65 + c0 + t] = yr[t] * yr[t] + yi[t] * yi[t];
    __syncthreads();

    // ---- fold probs through Zw into this slice's 8 output channels
#pragma unroll 8
    for (int t = 0; t < 64; ++t) {
        float pr = lds_prob[lane * 65 + t];
        const float4 z0 = *(const float4*)(g_Zw + (t << 6) + c0);
        const float4 z1 = *(const float4*)(g_Zw + (t << 6) + c0 + 4);
        acc[0] += pr * z0.x; acc[1] += pr * z0.y;
        acc[2] += pr * z0.z; acc[3] += pr * z0.w;
        acc[4] += pr * z1.x; acc[5] += pr * z1.y;
        acc[6] += pr * z1.z; acc[7] += pr * z1.w;
    }

    // ---- coalesced store: out[b][c][h][w]
    int ob = (b << 18) + (h << 6) + w;
#pragma unroll
    for (int k = 0; k < 8; ++k) {
        out[ob + ((c0 + k) << 12)] = acc[k] + g_cb[c0 + k];
    }
}

// ---------------------------------------------------------------------------
extern "C" void kernel_launch(void* const* d_in, const int* in_sizes, int n_in,
                              void* d_out, int out_size, void* d_ws, size_t ws_size,
                              hipStream_t stream) {
    const float* x     = (const float*)d_in[0];
    const float* style = (const float*)d_in[1];
    const float* dw    = (const float*)d_in[2];
    const float* dpb   = (const float*)d_in[3];
    const float* s2dw  = (const float*)d_in[4];
    const float* s2db  = (const float*)d_in[5];
    const float* qcnn  = (const float*)d_in[6];
    const float* meas  = (const float*)d_in[7];
    const float* outw  = (const float*)d_in[8];
    const float* outb  = (const float*)d_in[9];
    const float* rw    = (const float*)d_in[10];
    const float* resb  = (const float*)d_in[11];
    float* out = (float*)d_out;

    hipLaunchKernelGGL(k_prep, dim3(145), dim3(256), 0, stream,
                       style, dw, rw, s2dw, s2db, qcnn, meas, outw, outb, resb);
    hipLaunchKernelGGL(k_main, dim3(512), dim3(512), 0, stream, x, dpb, out);
}